// Round 2
// baseline (1351.044 us; speedup 1.0000x reference)
//
#include <hip/hip_runtime.h>
#include <hip/hip_bf16.h>
#include <math.h>

#define N_NODES 100000
#define N_EDGES 3200000
#define NFEAT 512
#define NHID 256
#define NCLASS 40
#define LDP 40   // padded LDS row stride in bf16 elems

#define N16 ((size_t)N_NODES * 16)
#define N8  ((size_t)N_NODES * 8)

typedef short bf16x8 __attribute__((ext_vector_type(8)));
typedef float f32x4 __attribute__((ext_vector_type(4)));

__device__ __forceinline__ unsigned short f2bf(float f) {
    unsigned int u = __builtin_bit_cast(unsigned int, f);
    u += 0x7fffu + ((u >> 16) & 1u);           // round-to-nearest-even
    return (unsigned short)(u >> 16);
}
__device__ __forceinline__ float bflo(unsigned int u) { return __builtin_bit_cast(float, u << 16); }
__device__ __forceinline__ float bfhi(unsigned int u) { return __builtin_bit_cast(float, u & 0xffff0000u); }

// ---------------- CSR build ----------------
__global__ void k_hist(const int* __restrict__ row, int* __restrict__ counts, int n) {
    int e = blockIdx.x * 256 + threadIdx.x;
    if (e < n) atomicAdd(&counts[row[e]], 1);
}

__global__ __launch_bounds__(256) void k_scanA(const int* __restrict__ counts, int* __restrict__ rowptr,
                                               int* __restrict__ bsums, int n) {
    __shared__ int sd[256];
    int t = threadIdx.x;
    int base = blockIdx.x * 1024 + t * 4;
    int v0 = (base + 0 < n) ? counts[base + 0] : 0;
    int v1 = (base + 1 < n) ? counts[base + 1] : 0;
    int v2 = (base + 2 < n) ? counts[base + 2] : 0;
    int v3 = (base + 3 < n) ? counts[base + 3] : 0;
    int s = v0 + v1 + v2 + v3;
    sd[t] = s;
    __syncthreads();
    for (int off = 1; off < 256; off <<= 1) {
        int x = (t >= off) ? sd[t - off] : 0;
        __syncthreads();
        sd[t] += x;
        __syncthreads();
    }
    int excl = sd[t] - s;
    if (base + 0 < n) rowptr[base + 0] = excl;
    if (base + 1 < n) rowptr[base + 1] = excl + v0;
    if (base + 2 < n) rowptr[base + 2] = excl + v0 + v1;
    if (base + 3 < n) rowptr[base + 3] = excl + v0 + v1 + v2;
    if (t == 255) bsums[blockIdx.x] = sd[255];
}

__global__ __launch_bounds__(128) void k_scanB(int* __restrict__ bsums, int* __restrict__ rowptr,
                                               int nblocks, int n) {
    __shared__ int sd[128];
    int t = threadIdx.x;
    int v = (t < nblocks) ? bsums[t] : 0;
    sd[t] = v;
    __syncthreads();
    for (int off = 1; off < 128; off <<= 1) {
        int x = (t >= off) ? sd[t - off] : 0;
        __syncthreads();
        sd[t] += x;
        __syncthreads();
    }
    if (t < nblocks) bsums[t] = sd[t] - v;   // exclusive block offset
    if (t == 127) rowptr[n] = sd[127];       // grand total
}

__global__ __launch_bounds__(256) void k_scanC(int* __restrict__ rowptr, int* __restrict__ cursor,
                                               const int* __restrict__ bsums, int n) {
    int t = threadIdx.x;
    int base = blockIdx.x * 1024 + t * 4;
    int off = bsums[blockIdx.x];
#pragma unroll
    for (int i = 0; i < 4; ++i) {
        int idx = base + i;
        if (idx < n) { int r = rowptr[idx] + off; rowptr[idx] = r; cursor[idx] = r; }
    }
}

__global__ void k_scatter(const int* __restrict__ row, const int* __restrict__ col,
                          const float* __restrict__ val, int* __restrict__ cursor,
                          uint2* __restrict__ pedge, int n) {
    int e = blockIdx.x * 256 + threadIdx.x;
    if (e < n) {
        int r = row[e];
        int pos = atomicAdd(&cursor[r], 1);
        uint2 ev;
        ev.x = (unsigned int)col[e];
        ev.y = __builtin_bit_cast(unsigned int, val[e]);
        pedge[pos] = ev;
    }
}

// ---------------- weight transpose + bf16 convert ----------------
__global__ void k_w1t(const float* __restrict__ W1, unsigned short* __restrict__ W1T) {
    int i = blockIdx.x * 256 + threadIdx.x;   // NHID*NFEAT
    int nn = i >> 9, k = i & 511;
    W1T[i] = f2bf(W1[k * NHID + nn]);
}
__global__ void k_w2t(const float* __restrict__ W2, unsigned short* __restrict__ W2T) {
    int i = blockIdx.x * 256 + threadIdx.x;   // 64*NHID
    int nn = i >> 8, k = i & 255;
    W2T[i] = (nn < NCLASS) ? f2bf(W2[k * NCLASS + nn]) : (unsigned short)0;
}

// ---------------- GEMM1: support_c[chunk][row][16] = bf16(x) @ bf16(W1) ----------------
// tile 128x256 (full NHID), 8 waves (2x4), x read once
__global__ __launch_bounds__(512) void k_gemm1(const float* __restrict__ X,
                                               const unsigned short* __restrict__ W1T,
                                               unsigned short* __restrict__ support_c) {
    __shared__ unsigned short As[128 * LDP];
    __shared__ unsigned short Bs[256 * LDP];
    const int t = threadIdx.x;
    const int lane = t & 63;
    const int w = t >> 6;
    const int wm = w >> 2, wn = w & 3;
    const int l15 = lane & 15, l4 = lane >> 4;
    const int bm = blockIdx.x;

    f32x4 acc[4][4];
#pragma unroll
    for (int m = 0; m < 4; ++m)
#pragma unroll
        for (int n = 0; n < 4; ++n) acc[m][n] = (f32x4){0.f, 0.f, 0.f, 0.f};

    // A staging: 128 rows x 32 k fp32 -> bf16; 512 thr x 8 elems
    const int arow = t >> 2, aq = t & 3;
    const long growA = (long)bm * 128 + arow;
    const bool avalid = growA < N_NODES;
    const float* xsrc = X + growA * NFEAT + aq * 8;
    unsigned short* adst = &As[arow * LDP + aq * 8];
    // B staging: 256 rows x 32 k bf16; 512 thr x 16 elems
    const int brow = t >> 1, bhalf = t & 1;
    const unsigned short* bsrc = W1T + (long)brow * NFEAT + bhalf * 16;
    unsigned short* bdst = &Bs[brow * LDP + bhalf * 16];

    for (int kt = 0; kt < NFEAT; kt += 32) {
        union { float4 v4[2]; float f[8]; } a;
        if (avalid) {
            a.v4[0] = *(const float4*)(xsrc + kt + 0);
            a.v4[1] = *(const float4*)(xsrc + kt + 4);
        } else {
            a.v4[0] = make_float4(0.f, 0.f, 0.f, 0.f);
            a.v4[1] = make_float4(0.f, 0.f, 0.f, 0.f);
        }
        union { uint4 q; unsigned short us[8]; } u;
#pragma unroll
        for (int j = 0; j < 8; ++j) u.us[j] = f2bf(a.f[j]);
        uint4 b0 = *(const uint4*)(bsrc + kt);
        uint4 b1v = *(const uint4*)(bsrc + kt + 8);
        *(uint4*)(adst) = u.q;
        *(uint4*)(bdst) = b0;
        *(uint4*)(bdst + 8) = b1v;
        __syncthreads();

        bf16x8 afr[4], bfr[4];
#pragma unroll
        for (int m = 0; m < 4; ++m)
            afr[m] = *(const bf16x8*)&As[(wm * 64 + m * 16 + l15) * LDP + l4 * 8];
#pragma unroll
        for (int n = 0; n < 4; ++n)
            bfr[n] = *(const bf16x8*)&Bs[(wn * 64 + n * 16 + l15) * LDP + l4 * 8];
#pragma unroll
        for (int m = 0; m < 4; ++m)
#pragma unroll
            for (int n = 0; n < 4; ++n)
                acc[m][n] = __builtin_amdgcn_mfma_f32_16x16x32_bf16(bfr[n], afr[m], acc[m][n], 0, 0, 0);
        __syncthreads();
    }
    // lane holds C[row=l15][cols=l4*4+0..3]; write chunked layout
#pragma unroll
    for (int m = 0; m < 4; ++m) {
        long row = (long)bm * 128 + wm * 64 + m * 16 + l15;
        if (row < N_NODES) {
#pragma unroll
            for (int n = 0; n < 4; ++n) {
                int colb = wn * 64 + n * 16 + l4 * 4;     // 0..255, (colb&15)==l4*4
                ushort4 o;
                o.x = f2bf(acc[m][n][0]);
                o.y = f2bf(acc[m][n][1]);
                o.z = f2bf(acc[m][n][2]);
                o.w = f2bf(acc[m][n][3]);
                *(ushort4*)&support_c[(size_t)(colb >> 4) * N16 + row * 16 + (colb & 15)] = o;
            }
        }
    }
}

// ---------------- SpMM1 chunked: h_c[chunk][row][16] = relu(A @ support + b1) ----------------
// grid (6250, 16); block 256 = 4 waves; wave does 4 rows; 8 edges x 8 lanes (2 cols each)
__global__ __launch_bounds__(256) void k_spmm1c(const int* __restrict__ rowptr,
                                                const uint2* __restrict__ pedge,
                                                const unsigned short* __restrict__ support_c,
                                                const float* __restrict__ b1,
                                                unsigned short* __restrict__ h_c) {
    const int chunk = blockIdx.y;
    const int lane = threadIdx.x & 63;
    const int eg = lane >> 3;     // edge subgroup 0..7
    const int cl = lane & 7;      // column pair 0..7
    const int wbase = blockIdx.x * 16 + (threadIdx.x >> 6) * 4;
    const unsigned short* Ssl = support_c + (size_t)chunk * N16;
    unsigned short* hsl = h_c + (size_t)chunk * N16;
    const float bb0 = b1[chunk * 16 + cl * 2];
    const float bb1 = b1[chunk * 16 + cl * 2 + 1];

#pragma unroll
    for (int i = 0; i < 4; ++i) {
        int row = wbase + i;
        if (row >= N_NODES) break;
        int beg = rowptr[row], end = rowptr[row + 1];
        float a0 = 0.f, a1 = 0.f;
        for (int e = beg + eg; e < end; e += 8) {
            uint2 ev = pedge[e];
            float v = __builtin_bit_cast(float, ev.y);
            unsigned int u = *(const unsigned int*)&Ssl[(size_t)ev.x * 16 + cl * 2];
            a0 = fmaf(v, bflo(u), a0);
            a1 = fmaf(v, bfhi(u), a1);
        }
#pragma unroll
        for (int off = 8; off < 64; off <<= 1) {
            a0 += __shfl_xor(a0, off, 64);
            a1 += __shfl_xor(a1, off, 64);
        }
        if (eg == 0) {
            float r0 = fmaxf(a0 + bb0, 0.f);
            float r1 = fmaxf(a1 + bb1, 0.f);
            unsigned int packed = (unsigned int)f2bf(r0) | ((unsigned int)f2bf(r1) << 16);
            *(unsigned int*)&hsl[(size_t)row * 16 + cl * 2] = packed;
        }
    }
}

// ---------------- GEMM2: logits2_c[chunk][row][8] = h @ W2 ----------------
__global__ __launch_bounds__(256) void k_gemm2(const unsigned short* __restrict__ h_c,
                                               const unsigned short* __restrict__ W2T,
                                               float* __restrict__ logits2_c) {
    __shared__ unsigned short As[128 * LDP];
    __shared__ unsigned short Bs[64 * LDP];
    const int t = threadIdx.x;
    const int lane = t & 63;
    const int w = t >> 6;
    const int wm = w >> 1, wn = w & 1;
    const int l15 = lane & 15, l4 = lane >> 4;
    const int bm = blockIdx.x;

    f32x4 acc[4][2];
#pragma unroll
    for (int m = 0; m < 4; ++m)
#pragma unroll
        for (int n = 0; n < 2; ++n) acc[m][n] = (f32x4){0.f, 0.f, 0.f, 0.f};

    const int srow = t >> 1, shalf = t & 1;
    const long grow = (long)bm * 128 + srow;
    const bool avalid = grow < N_NODES;
    const int bn2 = t >> 2, bq = t & 3;
    const unsigned short* bsrc = W2T + bn2 * NHID + bq * 8;

    for (int kt = 0; kt < NHID; kt += 32) {
        // A from chunked h: cols [kt+shalf*16 .. +15] live in chunk (kt>>4)+shalf
        const unsigned short* ap = h_c + (size_t)((kt >> 4) + shalf) * N16 + (size_t)grow * 16;
        uint4 a0, a1;
        if (avalid) {
            a0 = *(const uint4*)(ap);
            a1 = *(const uint4*)(ap + 8);
        } else {
            a0 = make_uint4(0, 0, 0, 0);
            a1 = make_uint4(0, 0, 0, 0);
        }
        uint4 bv = *(const uint4*)(bsrc + kt);
        *(uint4*)&As[srow * LDP + shalf * 16] = a0;
        *(uint4*)&As[srow * LDP + shalf * 16 + 8] = a1;
        *(uint4*)&Bs[bn2 * LDP + bq * 8] = bv;
        __syncthreads();

        bf16x8 afr[4], bfr[2];
#pragma unroll
        for (int m = 0; m < 4; ++m)
            afr[m] = *(const bf16x8*)&As[(wm * 64 + m * 16 + l15) * LDP + l4 * 8];
#pragma unroll
        for (int n = 0; n < 2; ++n)
            bfr[n] = *(const bf16x8*)&Bs[(wn * 32 + n * 16 + l15) * LDP + l4 * 8];
#pragma unroll
        for (int m = 0; m < 4; ++m)
#pragma unroll
            for (int n = 0; n < 2; ++n)
                acc[m][n] = __builtin_amdgcn_mfma_f32_16x16x32_bf16(bfr[n], afr[m], acc[m][n], 0, 0, 0);
        __syncthreads();
    }
#pragma unroll
    for (int m = 0; m < 4; ++m) {
        long row = (long)bm * 128 + wm * 64 + m * 16 + l15;
        if (row < N_NODES) {
#pragma unroll
            for (int n = 0; n < 2; ++n) {
                int colb = wn * 32 + n * 16 + l4 * 4;   // (colb&7) in {0,4}
                if (colb < NCLASS)
                    *(f32x4*)&logits2_c[(size_t)(colb >> 3) * N8 + (size_t)row * 8 + (colb & 7)] = acc[m][n];
            }
        }
    }
}

// ---------------- SpMM2 chunked: tmp2[row][40] = A @ logits2 + b2 ----------------
// grid (6250, 5); 8 edges x 8 lanes (1 col each)
__global__ __launch_bounds__(256) void k_spmm2c(const int* __restrict__ rowptr,
                                                const uint2* __restrict__ pedge,
                                                const float* __restrict__ logits2_c,
                                                const float* __restrict__ b2,
                                                float* __restrict__ tmp2) {
    const int chunk = blockIdx.y;
    const int lane = threadIdx.x & 63;
    const int eg = lane >> 3;
    const int cl = lane & 7;
    const int wbase = blockIdx.x * 16 + (threadIdx.x >> 6) * 4;
    const float* Lsl = logits2_c + (size_t)chunk * N8;
    const float bb = b2[chunk * 8 + cl];

#pragma unroll
    for (int i = 0; i < 4; ++i) {
        int row = wbase + i;
        if (row >= N_NODES) break;
        int beg = rowptr[row], end = rowptr[row + 1];
        float a = 0.f;
        for (int e = beg + eg; e < end; e += 8) {
            uint2 ev = pedge[e];
            float v = __builtin_bit_cast(float, ev.y);
            float g = Lsl[(size_t)ev.x * 8 + cl];
            a = fmaf(v, g, a);
        }
#pragma unroll
        for (int off = 8; off < 64; off <<= 1) a += __shfl_xor(a, off, 64);
        if (eg == 0) tmp2[(size_t)row * 40 + chunk * 8 + cl] = a + bb;
    }
}

// ---------------- log_softmax over 40 classes, wave per row ----------------
__global__ __launch_bounds__(256) void k_lsm(const float* __restrict__ tmp2, float* __restrict__ out) {
    int row = blockIdx.x * 4 + (threadIdx.x >> 6);
    int lane = threadIdx.x & 63;
    if (row >= N_NODES) return;
    bool act = lane < NCLASS;
    float v = act ? tmp2[(size_t)row * 40 + lane] : -INFINITY;
    float mv = v;
#pragma unroll
    for (int off = 32; off; off >>= 1) mv = fmaxf(mv, __shfl_xor(mv, off, 64));
    float p = act ? __expf(v - mv) : 0.f;
    float s = p;
#pragma unroll
    for (int off = 32; off; off >>= 1) s += __shfl_xor(s, off, 64);
    if (act) out[(size_t)row * 40 + lane] = v - mv - __logf(s);
}

extern "C" void kernel_launch(void* const* d_in, const int* in_sizes, int n_in,
                              void* d_out, int out_size, void* d_ws, size_t ws_size,
                              hipStream_t stream) {
    const float* x    = (const float*)d_in[0];
    const int*   erow = (const int*)d_in[1];
    const int*   ecol = (const int*)d_in[2];
    const float* eval_ = (const float*)d_in[3];
    const float* W1   = (const float*)d_in[4];
    const float* b1   = (const float*)d_in[5];
    const float* W2   = (const float*)d_in[6];
    const float* b2   = (const float*)d_in[7];
    float* out = (float*)d_out;

    char* p = (char*)d_ws;
    auto alloc = [&](size_t b) { char* r = p; p += (b + 255) & ~(size_t)255; return r; };
    int* counts            = (int*)alloc((size_t)N_NODES * 4);
    int* rowptr            = (int*)alloc((size_t)(N_NODES + 1) * 4);
    int* cursor            = (int*)alloc((size_t)N_NODES * 4);
    int* bsums             = (int*)alloc(512);
    uint2* pedge           = (uint2*)alloc((size_t)N_EDGES * 8);
    unsigned short* W1T    = (unsigned short*)alloc((size_t)NHID * NFEAT * 2);
    unsigned short* W2T    = (unsigned short*)alloc((size_t)64 * NHID * 2);
    unsigned short* support_c = (unsigned short*)alloc((size_t)N_NODES * NHID * 2);
    unsigned short* h_c    = (unsigned short*)alloc((size_t)N_NODES * NHID * 2);
    float* logits2_c       = (float*)alloc((size_t)N_NODES * 40 * 4);
    float* tmp2            = (float*)alloc((size_t)N_NODES * 40 * 4);

    hipMemsetAsync(counts, 0, (size_t)N_NODES * 4, stream);
    k_hist<<<(N_EDGES + 255) / 256, 256, 0, stream>>>(erow, counts, N_EDGES);
    k_scanA<<<98, 256, 0, stream>>>(counts, rowptr, bsums, N_NODES);
    k_scanB<<<1, 128, 0, stream>>>(bsums, rowptr, 98, N_NODES);
    k_scanC<<<98, 256, 0, stream>>>(rowptr, cursor, bsums, N_NODES);
    k_scatter<<<(N_EDGES + 255) / 256, 256, 0, stream>>>(erow, ecol, eval_, cursor, pedge, N_EDGES);
    k_w1t<<<(NHID * NFEAT) / 256, 256, 0, stream>>>(W1, W1T);
    k_w2t<<<(64 * NHID) / 256, 256, 0, stream>>>(W2, W2T);
    k_gemm1<<<(N_NODES + 127) / 128, 512, 0, stream>>>(x, W1T, support_c);
    k_spmm1c<<<dim3(6250, 16), 256, 0, stream>>>(rowptr, pedge, support_c, b1, h_c);
    k_gemm2<<<(N_NODES + 127) / 128, 256, 0, stream>>>(h_c, W2T, logits2_c);
    k_spmm2c<<<dim3(6250, 5), 256, 0, stream>>>(rowptr, pedge, logits2_c, b2, tmp2);
    k_lsm<<<25000, 256, 0, stream>>>(tmp2, out);
}

// Round 4
// 868.636 us; speedup vs baseline: 1.5554x; 1.5554x over previous
//
#include <hip/hip_runtime.h>
#include <hip/hip_bf16.h>
#include <math.h>

#define N_NODES 100000
#define N_EDGES 3200000
#define NFEAT 512
#define NHID 256
#define NCLASS 40
#define LDP 40   // padded LDS row stride in bf16 elems

typedef short bf16x8 __attribute__((ext_vector_type(8)));
typedef float f32x4 __attribute__((ext_vector_type(4)));
typedef unsigned long long u64;

__device__ __forceinline__ unsigned short f2bf(float f) {
    unsigned int u = __builtin_bit_cast(unsigned int, f);
    u += 0x7fffu + ((u >> 16) & 1u);           // round-to-nearest-even
    return (unsigned short)(u >> 16);
}
__device__ __forceinline__ float bflo(unsigned int u) { return __builtin_bit_cast(float, u << 16); }
__device__ __forceinline__ float bfhi(unsigned int u) { return __builtin_bit_cast(float, u & 0xffff0000u); }
__device__ __forceinline__ unsigned int ecol_of(u64 ev) { return (unsigned int)(ev & 0xffffffffu); }
__device__ __forceinline__ float eval_of(u64 ev) { return __builtin_bit_cast(float, (unsigned int)(ev >> 32)); }

// ---------------- CSR build ----------------
__global__ void k_hist(const int* __restrict__ row, int* __restrict__ counts, int n) {
    int e = blockIdx.x * 256 + threadIdx.x;
    if (e < n) atomicAdd(&counts[row[e]], 1);
}

__global__ __launch_bounds__(256) void k_scanA(const int* __restrict__ counts, int* __restrict__ rowptr,
                                               int* __restrict__ bsums, int n) {
    __shared__ int sd[256];
    int t = threadIdx.x;
    int base = blockIdx.x * 1024 + t * 4;
    int v0 = (base + 0 < n) ? counts[base + 0] : 0;
    int v1 = (base + 1 < n) ? counts[base + 1] : 0;
    int v2 = (base + 2 < n) ? counts[base + 2] : 0;
    int v3 = (base + 3 < n) ? counts[base + 3] : 0;
    int s = v0 + v1 + v2 + v3;
    sd[t] = s;
    __syncthreads();
    for (int off = 1; off < 256; off <<= 1) {
        int x = (t >= off) ? sd[t - off] : 0;
        __syncthreads();
        sd[t] += x;
        __syncthreads();
    }
    int excl = sd[t] - s;
    if (base + 0 < n) rowptr[base + 0] = excl;
    if (base + 1 < n) rowptr[base + 1] = excl + v0;
    if (base + 2 < n) rowptr[base + 2] = excl + v0 + v1;
    if (base + 3 < n) rowptr[base + 3] = excl + v0 + v1 + v2;
    if (t == 255) bsums[blockIdx.x] = sd[255];
}

__global__ __launch_bounds__(128) void k_scanB(int* __restrict__ bsums, int* __restrict__ rowptr,
                                               int nblocks, int n) {
    __shared__ int sd[128];
    int t = threadIdx.x;
    int v = (t < nblocks) ? bsums[t] : 0;
    sd[t] = v;
    __syncthreads();
    for (int off = 1; off < 128; off <<= 1) {
        int x = (t >= off) ? sd[t - off] : 0;
        __syncthreads();
        sd[t] += x;
        __syncthreads();
    }
    if (t < nblocks) bsums[t] = sd[t] - v;   // exclusive block offset
    if (t == 127) rowptr[n] = sd[127];       // grand total
}

__global__ __launch_bounds__(256) void k_scanC(int* __restrict__ rowptr, int* __restrict__ cursor,
                                               const int* __restrict__ bsums, int n) {
    int t = threadIdx.x;
    int base = blockIdx.x * 1024 + t * 4;
    int off = bsums[blockIdx.x];
#pragma unroll
    for (int i = 0; i < 4; ++i) {
        int idx = base + i;
        if (idx < n) { int r = rowptr[idx] + off; rowptr[idx] = r; cursor[idx] = r; }
    }
}

__global__ void k_scatter(const int* __restrict__ row, const int* __restrict__ col,
                          const float* __restrict__ val, int* __restrict__ cursor,
                          u64* __restrict__ pedge, int n) {
    int e = blockIdx.x * 256 + threadIdx.x;
    if (e < n) {
        int r = row[e];
        int pos = atomicAdd(&cursor[r], 1);
        u64 ev = (u64)(unsigned int)col[e] |
                 ((u64)__builtin_bit_cast(unsigned int, val[e]) << 32);
        pedge[pos] = ev;
    }
}

// ---------------- weight transpose + bf16 convert ----------------
__global__ void k_w1t(const float* __restrict__ W1, unsigned short* __restrict__ W1T) {
    int i = blockIdx.x * 256 + threadIdx.x;   // NHID*NFEAT
    int nn = i >> 9, k = i & 511;
    W1T[i] = f2bf(W1[k * NHID + nn]);
}
__global__ void k_w2t(const float* __restrict__ W2, unsigned short* __restrict__ W2T) {
    int i = blockIdx.x * 256 + threadIdx.x;   // 64*NHID
    int nn = i >> 8, k = i & 255;
    W2T[i] = (nn < NCLASS) ? f2bf(W2[k * NCLASS + nn]) : (unsigned short)0;
}

// ---------------- GEMM1: support[row][256] = bf16(x) @ bf16(W1) ----------------
// tile 128x256 (full NHID), 8 waves (2x4), x read once
__global__ __launch_bounds__(512) void k_gemm1(const float* __restrict__ X,
                                               const unsigned short* __restrict__ W1T,
                                               unsigned short* __restrict__ support) {
    __shared__ unsigned short As[128 * LDP];
    __shared__ unsigned short Bs[256 * LDP];
    const int t = threadIdx.x;
    const int lane = t & 63;
    const int w = t >> 6;
    const int wm = w >> 2, wn = w & 3;
    const int l15 = lane & 15, l4 = lane >> 4;
    const int bm = blockIdx.x;

    f32x4 acc[4][4];
#pragma unroll
    for (int m = 0; m < 4; ++m)
#pragma unroll
        for (int n = 0; n < 4; ++n) acc[m][n] = (f32x4){0.f, 0.f, 0.f, 0.f};

    // A staging: 128 rows x 32 k fp32 -> bf16; 512 thr x 8 elems
    const int arow = t >> 2, aq = t & 3;
    const long growA = (long)bm * 128 + arow;
    const bool avalid = growA < N_NODES;
    const float* xsrc = X + growA * NFEAT + aq * 8;
    unsigned short* adst = &As[arow * LDP + aq * 8];
    // B staging: 256 rows x 32 k bf16; 512 thr x 16 elems
    const int brow = t >> 1, bhalf = t & 1;
    const unsigned short* bsrc = W1T + (long)brow * NFEAT + bhalf * 16;
    unsigned short* bdst = &Bs[brow * LDP + bhalf * 16];

    for (int kt = 0; kt < NFEAT; kt += 32) {
        union { float4 v4[2]; float f[8]; } a;
        if (avalid) {
            a.v4[0] = *(const float4*)(xsrc + kt + 0);
            a.v4[1] = *(const float4*)(xsrc + kt + 4);
        } else {
            a.v4[0] = make_float4(0.f, 0.f, 0.f, 0.f);
            a.v4[1] = make_float4(0.f, 0.f, 0.f, 0.f);
        }
        union { uint4 q; unsigned short us[8]; } u;
#pragma unroll
        for (int j = 0; j < 8; ++j) u.us[j] = f2bf(a.f[j]);
        uint4 b0 = *(const uint4*)(bsrc + kt);
        uint4 b1v = *(const uint4*)(bsrc + kt + 8);
        *(uint4*)(adst) = u.q;
        *(uint4*)(bdst) = b0;
        *(uint4*)(bdst + 8) = b1v;
        __syncthreads();

        bf16x8 afr[4], bfr[4];
#pragma unroll
        for (int m = 0; m < 4; ++m)
            afr[m] = *(const bf16x8*)&As[(wm * 64 + m * 16 + l15) * LDP + l4 * 8];
#pragma unroll
        for (int n = 0; n < 4; ++n)
            bfr[n] = *(const bf16x8*)&Bs[(wn * 64 + n * 16 + l15) * LDP + l4 * 8];
#pragma unroll
        for (int m = 0; m < 4; ++m)
#pragma unroll
            for (int n = 0; n < 4; ++n)
                acc[m][n] = __builtin_amdgcn_mfma_f32_16x16x32_bf16(bfr[n], afr[m], acc[m][n], 0, 0, 0);
        __syncthreads();
    }
    // lane holds C[row=l15][cols=l4*4+0..3]; row-major write
#pragma unroll
    for (int m = 0; m < 4; ++m) {
        long row = (long)bm * 128 + wm * 64 + m * 16 + l15;
        if (row < N_NODES) {
#pragma unroll
            for (int n = 0; n < 4; ++n) {
                int colb = wn * 64 + n * 16 + l4 * 4;
                ushort4 o;
                o.x = f2bf(acc[m][n][0]);
                o.y = f2bf(acc[m][n][1]);
                o.z = f2bf(acc[m][n][2]);
                o.w = f2bf(acc[m][n][3]);
                *(ushort4*)&support[(size_t)row * NHID + colb] = o;
            }
        }
    }
}

// ---------------- SpMM1 + bias + ReLU -> h (bf16). one wave per row, 4-way MLP ----------------
__global__ __launch_bounds__(256) void k_spmm1(const int* __restrict__ rowptr,
                                               const u64* __restrict__ pedge,
                                               const unsigned short* __restrict__ support,
                                               const float* __restrict__ b1,
                                               unsigned short* __restrict__ h) {
    int wrow = (blockIdx.x * 256 + threadIdx.x) >> 6;
    int lane = threadIdx.x & 63;
    if (wrow >= N_NODES) return;
    int beg = rowptr[wrow], end = rowptr[wrow + 1];
    float a0 = 0.f, a1 = 0.f, a2 = 0.f, a3 = 0.f;
    const int c4 = lane * 4;
    int e = beg;
    for (; e + 4 <= end; e += 4) {
        u64 ev0 = __builtin_nontemporal_load(&pedge[e + 0]);
        u64 ev1 = __builtin_nontemporal_load(&pedge[e + 1]);
        u64 ev2 = __builtin_nontemporal_load(&pedge[e + 2]);
        u64 ev3 = __builtin_nontemporal_load(&pedge[e + 3]);
        uint2 g0 = *(const uint2*)&support[(size_t)ecol_of(ev0) * NHID + c4];
        uint2 g1 = *(const uint2*)&support[(size_t)ecol_of(ev1) * NHID + c4];
        uint2 g2 = *(const uint2*)&support[(size_t)ecol_of(ev2) * NHID + c4];
        uint2 g3 = *(const uint2*)&support[(size_t)ecol_of(ev3) * NHID + c4];
        float v0 = eval_of(ev0);
        float v1 = eval_of(ev1);
        float v2 = eval_of(ev2);
        float v3 = eval_of(ev3);
        a0 = fmaf(v0, bflo(g0.x), a0); a1 = fmaf(v0, bfhi(g0.x), a1);
        a2 = fmaf(v0, bflo(g0.y), a2); a3 = fmaf(v0, bfhi(g0.y), a3);
        a0 = fmaf(v1, bflo(g1.x), a0); a1 = fmaf(v1, bfhi(g1.x), a1);
        a2 = fmaf(v1, bflo(g1.y), a2); a3 = fmaf(v1, bfhi(g1.y), a3);
        a0 = fmaf(v2, bflo(g2.x), a0); a1 = fmaf(v2, bfhi(g2.x), a1);
        a2 = fmaf(v2, bflo(g2.y), a2); a3 = fmaf(v2, bfhi(g2.y), a3);
        a0 = fmaf(v3, bflo(g3.x), a0); a1 = fmaf(v3, bfhi(g3.x), a1);
        a2 = fmaf(v3, bflo(g3.y), a2); a3 = fmaf(v3, bfhi(g3.y), a3);
    }
    for (; e < end; ++e) {
        u64 ev = __builtin_nontemporal_load(&pedge[e]);
        float v = eval_of(ev);
        uint2 g = *(const uint2*)&support[(size_t)ecol_of(ev) * NHID + c4];
        a0 = fmaf(v, bflo(g.x), a0); a1 = fmaf(v, bfhi(g.x), a1);
        a2 = fmaf(v, bflo(g.y), a2); a3 = fmaf(v, bfhi(g.y), a3);
    }
    float4 bb = *(const float4*)&b1[c4];
    a0 = fmaxf(a0 + bb.x, 0.f);
    a1 = fmaxf(a1 + bb.y, 0.f);
    a2 = fmaxf(a2 + bb.z, 0.f);
    a3 = fmaxf(a3 + bb.w, 0.f);
    ushort4 o;
    o.x = f2bf(a0); o.y = f2bf(a1); o.z = f2bf(a2); o.w = f2bf(a3);
    *(ushort4*)&h[(size_t)wrow * NHID + c4] = o;
}

// ---------------- GEMM2: logits2[row][40] = h @ W2 (fp32 out) ----------------
__global__ __launch_bounds__(256) void k_gemm2(const unsigned short* __restrict__ H,
                                               const unsigned short* __restrict__ W2T,
                                               float* __restrict__ logits2) {
    __shared__ unsigned short As[128 * LDP];
    __shared__ unsigned short Bs[64 * LDP];
    const int t = threadIdx.x;
    const int lane = t & 63;
    const int w = t >> 6;
    const int wm = w >> 1, wn = w & 1;
    const int l15 = lane & 15, l4 = lane >> 4;
    const int bm = blockIdx.x;

    f32x4 acc[4][2];
#pragma unroll
    for (int m = 0; m < 4; ++m)
#pragma unroll
        for (int n = 0; n < 2; ++n) acc[m][n] = (f32x4){0.f, 0.f, 0.f, 0.f};

    const int srow = t >> 1, shalf = t & 1;
    const long grow = (long)bm * 128 + srow;
    const bool avalid = grow < N_NODES;
    const unsigned short* asrc = H + grow * NHID + shalf * 16;
    const int bn2 = t >> 2, bq = t & 3;
    const unsigned short* bsrc = W2T + bn2 * NHID + bq * 8;

    for (int kt = 0; kt < NHID; kt += 32) {
        uint4 a0, a1;
        if (avalid) {
            a0 = *(const uint4*)(asrc + kt);
            a1 = *(const uint4*)(asrc + kt + 8);
        } else {
            a0 = make_uint4(0, 0, 0, 0);
            a1 = make_uint4(0, 0, 0, 0);
        }
        uint4 bv = *(const uint4*)(bsrc + kt);
        *(uint4*)&As[srow * LDP + shalf * 16] = a0;
        *(uint4*)&As[srow * LDP + shalf * 16 + 8] = a1;
        *(uint4*)&Bs[bn2 * LDP + bq * 8] = bv;
        __syncthreads();

        bf16x8 afr[4], bfr[2];
#pragma unroll
        for (int m = 0; m < 4; ++m)
            afr[m] = *(const bf16x8*)&As[(wm * 64 + m * 16 + l15) * LDP + l4 * 8];
#pragma unroll
        for (int n = 0; n < 2; ++n)
            bfr[n] = *(const bf16x8*)&Bs[(wn * 32 + n * 16 + l15) * LDP + l4 * 8];
#pragma unroll
        for (int m = 0; m < 4; ++m)
#pragma unroll
            for (int n = 0; n < 2; ++n)
                acc[m][n] = __builtin_amdgcn_mfma_f32_16x16x32_bf16(bfr[n], afr[m], acc[m][n], 0, 0, 0);
        __syncthreads();
    }
#pragma unroll
    for (int m = 0; m < 4; ++m) {
        long row = (long)bm * 128 + wm * 64 + m * 16 + l15;
        if (row < N_NODES) {
#pragma unroll
            for (int n = 0; n < 2; ++n) {
                int colb = wn * 32 + n * 16 + l4 * 4;
                if (colb < NCLASS)
                    *(f32x4*)&logits2[(size_t)row * NCLASS + colb] = acc[m][n];
            }
        }
    }
}

// ---------------- SpMM2 + bias + log_softmax -> out (fp32). one wave per row, 4-way MLP ----------------
__global__ __launch_bounds__(256) void k_spmm2(const int* __restrict__ rowptr,
                                               const u64* __restrict__ pedge,
                                               const float* __restrict__ logits2,
                                               const float* __restrict__ b2, float* __restrict__ out) {
    int wrow = (blockIdx.x * 256 + threadIdx.x) >> 6;
    int lane = threadIdx.x & 63;
    if (wrow >= N_NODES) return;
    int beg = rowptr[wrow], end = rowptr[wrow + 1];
    bool act = lane < NCLASS;
    int colidx = act ? lane : 0;
    float acc = 0.f;
    int e = beg;
    for (; e + 4 <= end; e += 4) {
        u64 ev0 = __builtin_nontemporal_load(&pedge[e + 0]);
        u64 ev1 = __builtin_nontemporal_load(&pedge[e + 1]);
        u64 ev2 = __builtin_nontemporal_load(&pedge[e + 2]);
        u64 ev3 = __builtin_nontemporal_load(&pedge[e + 3]);
        float g0 = logits2[(size_t)ecol_of(ev0) * NCLASS + colidx];
        float g1 = logits2[(size_t)ecol_of(ev1) * NCLASS + colidx];
        float g2 = logits2[(size_t)ecol_of(ev2) * NCLASS + colidx];
        float g3 = logits2[(size_t)ecol_of(ev3) * NCLASS + colidx];
        acc = fmaf(eval_of(ev0), g0, acc);
        acc = fmaf(eval_of(ev1), g1, acc);
        acc = fmaf(eval_of(ev2), g2, acc);
        acc = fmaf(eval_of(ev3), g3, acc);
    }
    for (; e < end; ++e) {
        u64 ev = __builtin_nontemporal_load(&pedge[e]);
        float g = logits2[(size_t)ecol_of(ev) * NCLASS + colidx];
        acc = fmaf(eval_of(ev), g, acc);
    }
    acc += b2[colidx];
    float mv = act ? acc : -INFINITY;
#pragma unroll
    for (int off = 32; off; off >>= 1) mv = fmaxf(mv, __shfl_xor(mv, off, 64));
    float p = act ? __expf(acc - mv) : 0.f;
    float s = p;
#pragma unroll
    for (int off = 32; off; off >>= 1) s += __shfl_xor(s, off, 64);
    if (act) out[(size_t)wrow * NCLASS + lane] = acc - mv - __logf(s);
}

extern "C" void kernel_launch(void* const* d_in, const int* in_sizes, int n_in,
                              void* d_out, int out_size, void* d_ws, size_t ws_size,
                              hipStream_t stream) {
    const float* x    = (const float*)d_in[0];
    const int*   erow = (const int*)d_in[1];
    const int*   ecol = (const int*)d_in[2];
    const float* eval_ = (const float*)d_in[3];
    const float* W1   = (const float*)d_in[4];
    const float* b1   = (const float*)d_in[5];
    const float* W2   = (const float*)d_in[6];
    const float* b2   = (const float*)d_in[7];
    float* out = (float*)d_out;

    char* p = (char*)d_ws;
    auto alloc = [&](size_t b) { char* r = p; p += (b + 255) & ~(size_t)255; return r; };
    int* counts            = (int*)alloc((size_t)N_NODES * 4);
    int* rowptr            = (int*)alloc((size_t)(N_NODES + 1) * 4);
    int* cursor            = (int*)alloc((size_t)N_NODES * 4);
    int* bsums             = (int*)alloc(512);
    u64* pedge             = (u64*)alloc((size_t)N_EDGES * 8);
    unsigned short* W1T    = (unsigned short*)alloc((size_t)NHID * NFEAT * 2);
    unsigned short* W2T    = (unsigned short*)alloc((size_t)64 * NHID * 2);
    unsigned short* support= (unsigned short*)alloc((size_t)N_NODES * NHID * 2);
    unsigned short* h      = (unsigned short*)alloc((size_t)N_NODES * NHID * 2);
    float* logits2         = (float*)alloc((size_t)N_NODES * NCLASS * 4);

    (void)hipMemsetAsync(counts, 0, (size_t)N_NODES * 4, stream);
    k_hist<<<(N_EDGES + 255) / 256, 256, 0, stream>>>(erow, counts, N_EDGES);
    k_scanA<<<98, 256, 0, stream>>>(counts, rowptr, bsums, N_NODES);
    k_scanB<<<1, 128, 0, stream>>>(bsums, rowptr, 98, N_NODES);
    k_scanC<<<98, 256, 0, stream>>>(rowptr, cursor, bsums, N_NODES);
    k_scatter<<<(N_EDGES + 255) / 256, 256, 0, stream>>>(erow, ecol, eval_, cursor, pedge, N_EDGES);
    k_w1t<<<(NHID * NFEAT) / 256, 256, 0, stream>>>(W1, W1T);
    k_w2t<<<(64 * NHID) / 256, 256, 0, stream>>>(W2, W2T);
    k_gemm1<<<(N_NODES + 127) / 128, 512, 0, stream>>>(x, W1T, support);
    k_spmm1<<<(N_NODES + 3) / 4, 256, 0, stream>>>(rowptr, pedge, support, b1, h);
    k_gemm2<<<(N_NODES + 127) / 128, 256, 0, stream>>>(h, W2T, logits2);
    k_spmm2<<<(N_NODES + 3) / 4, 256, 0, stream>>>(rowptr, pedge, logits2, b2, out);
}